// Round 8
// baseline (121.160 us; speedup 1.0000x reference)
//
#include <hip/hip_runtime.h>
#include <hip/hip_bf16.h>
#include <stdint.h>

#define B_SZ  8192
#define IN_SZ 1024
#define H_SZ  1024
#define K_BR  4
#define BR_SZ 512
#define J_SZ  2048   // IN + H (GEMM K dim)
#define BK    64     // K-step
#define NT    (J_SZ / BK)   // 32 K-tiles
#define BM    128
#define BN    64

#define FIX_THR 0.08f        // flag |0.5*v-1| < THR for exact fp32 recompute
#define MAXFIX  (1 << 20)    // 1M entries, 4MB

typedef __attribute__((ext_vector_type(8))) short  short8;   // 8 bf16
typedef __attribute__((ext_vector_type(4))) float  f32x4;

__device__ __forceinline__ unsigned short f2bf(float f) {
    union { __hip_bfloat16 b; unsigned short u; } cv;
    cv.b = __float2bfloat16(f);
    return cv.u;
}

__device__ __forceinline__ void gl_lds16(const void* g, void* l) {
    __builtin_amdgcn_global_load_lds(
        (const __attribute__((address_space(1))) void*)g,
        (__attribute__((address_space(3))) void*)l, 16, 0, 0);
}

// ---- prep: alpha = sigmoid(taus), biasw[h] = sum_k (1-alpha)*b[k,h]; zero cnt ----
__global__ void prep_alpha(const float* __restrict__ taus, const float* __restrict__ bvec,
                           float* __restrict__ alpha, float* __restrict__ biasw,
                           int* __restrict__ cnt) {
    int h = blockIdx.x * blockDim.x + threadIdx.x;
    if (h == 0) *cnt = 0;
    if (h >= H_SZ) return;
    float bsum = 0.f;
    for (int k = 0; k < K_BR; ++k) {
        float a = 1.f / (1.f + expf(-taus[k * H_SZ + h]));
        alpha[k * H_SZ + h] = a;
        bsum += (1.f - a) * bvec[k * H_SZ + h];
    }
    biasw[h] = bsum;
}

// ---- prep 2: Wt[h][k*512+i] = (1-sigmoid(taus[k,h])) * W[k,h,i]  (bf16, B^T) ----
__global__ void build_wt(const float* __restrict__ W, const float* __restrict__ taus,
                         unsigned short* __restrict__ Wt) {
    int t = blockIdx.x * 256 + threadIdx.x;
    int e0 = t * 8;
    if (e0 >= H_SZ * J_SZ) return;
    int h  = e0 >> 11;
    int j0 = e0 & 2047;
    int k  = j0 >> 9;
    int i0 = j0 & 511;
    float a = 1.f / (1.f + expf(-taus[k * H_SZ + h]));
    float s = 1.f - a;
    const float* src = W + ((size_t)(k * H_SZ + h)) * BR_SZ + i0;
    union { short8 v; unsigned short u[8]; } o;
    #pragma unroll
    for (int q = 0; q < 8; ++q) o.u[q] = f2bf(s * src[q]);
    *(short8*)(Wt + (size_t)h * J_SZ + j0) = o.v;
}

// ---- prep 3: Xb[b][j] = bf16(concat(input_t, hidden)[b][j]) ----
__global__ void build_xb(const float* __restrict__ inp, const float* __restrict__ hid,
                         unsigned short* __restrict__ Xb) {
    int t = blockIdx.x * 256 + threadIdx.x;
    long long e0 = (long long)t * 8;
    if (e0 >= (long long)B_SZ * J_SZ) return;
    int b  = (int)(e0 >> 11);
    int j0 = (int)(e0 & 2047);
    const float* src = (j0 < IN_SZ) ? (inp + (size_t)b * IN_SZ + j0)
                                    : (hid + (size_t)b * H_SZ + (j0 - IN_SZ));
    union { short8 v; unsigned short u[8]; } o;
    #pragma unroll
    for (int q = 0; q < 8; ++q) o.u[q] = f2bf(src[q]);
    *(short8*)(Xb + (size_t)b * J_SZ + j0) = o.v;
}

// ---- main: 128x64 bf16 MFMA GEMM, BK=64 dbuf, swizzled LDS, XCD-swizzled grid,
//      3 blocks/CU for TLP + cohort-staggered epilogue overlap ----
__global__ void __launch_bounds__(512, 6)
gemm_fused_ep(const unsigned short* __restrict__ Xb,
              const unsigned short* __restrict__ Wt,
              const float* __restrict__ alpha,
              const float* __restrict__ biasw,
              const float* __restrict__ bs,
              float* __restrict__ out,
              int* __restrict__ cnt,
              int* __restrict__ list) {
    __shared__ char smem[49152];   // A dbuf 32KB | B dbuf 16KB ; epilogue overlay f32[128][64]=32KB
    const int tid  = threadIdx.x;
    const int wid  = tid >> 6;          // 0..7
    const int lane = tid & 63;

    // XCD-aware bijective swizzle: 1024 blocks = 8 XCDs x 128.
    // Consecutive wgid on one XCD share the same N-panel (Wt stays L2-hot).
    const int orig = blockIdx.x;
    const int wgid = (orig & 7) * 128 + (orig >> 3);
    const int m_idx = wgid & 63;        // 0..63
    const int n_idx = wgid >> 6;        // 0..15
    const int bm0  = m_idx * BM;
    const int bn0  = n_idx * BN;

    const int wm   = (wid >> 2) * 64;   // 2 wave-rows of 64
    const int wn   = (wid & 3) * 16;    // 4 wave-cols of 16

    f32x4 acc[4];
    #pragma unroll
    for (int mi = 0; mi < 4; ++mi) acc[mi] = (f32x4){0.f, 0.f, 0.f, 0.f};

    const int hi = lane >> 4;     // 0..3 k-slot selector
    const int rm = lane & 15;

    const int srow  = lane >> 3;  // row within chunk
    const int sslot = lane & 7;   // 16B slot within 128B row

#define AB(b) ((char*)smem + (b) * 16384)
#define BB(b) ((char*)smem + 32768 + (b) * 8192)

    // A: 16 chunks of 1KB (8 rows each); wave stages chunks wid*2, wid*2+1.
    // B: 8 chunks of 1KB; wave stages chunk wid.
#define STAGE(kt, b)                                                          \
    {                                                                         \
        _Pragma("unroll")                                                     \
        for (int p = 0; p < 2; ++p) {                                         \
            int c    = wid * 2 + p;                                           \
            int row  = c * 8 + srow;                                          \
            int sw   = sslot ^ (row & 7);                                     \
            gl_lds16(Xb + (size_t)(bm0 + row) * J_SZ + (kt) + sw * 8,         \
                     AB(b) + c * 1024);                                       \
        }                                                                     \
        {                                                                     \
            int row = wid * 8 + srow;                                         \
            int sw  = sslot ^ (row & 7);                                      \
            gl_lds16(Wt + (size_t)(bn0 + row) * J_SZ + (kt) + sw * 8,         \
                     BB(b) + wid * 1024);                                     \
        }                                                                     \
    }

    STAGE(0, 0);
    __syncthreads();

    int cur = 0;
    for (int t = 0; t < NT; ++t) {
        if (t + 1 < NT) STAGE((t + 1) * BK, cur ^ 1);

        #pragma unroll
        for (int h2 = 0; h2 < 2; ++h2) {        // k halves 0..31, 32..63
            const int s0 = h2 * 4 + hi;         // 16B slot pre-swizzle
            short8 af[4], bf;
            #pragma unroll
            for (int mi = 0; mi < 4; ++mi) {
                int m = wm + mi * 16 + rm;
                af[mi] = *(const short8*)(AB(cur) + m * 128 + ((s0 ^ (m & 7)) << 4));
            }
            {
                int n = wn + rm;
                bf = *(const short8*)(BB(cur) + n * 128 + ((s0 ^ (n & 7)) << 4));
            }
            #pragma unroll
            for (int mi = 0; mi < 4; ++mi)
                acc[mi] = __builtin_amdgcn_mfma_f32_16x16x32_bf16(
                              af[mi], bf, acc[mi], 0, 0, 0);
        }
        __syncthreads();
        cur ^= 1;
    }
#undef STAGE
#undef AB
#undef BB

    // ---- fused epilogue: acc -> LDS overlay, coalesced bias+bs+spike+flag ----
    float* Alds = (float*)smem;            // f32[128][64], 32KB (A bufs dead)
    const int rr = hi * 4;                 // C/D row base: (lane>>4)*4 + reg
    {
        int cl = wn + rm;
        #pragma unroll
        for (int mi = 0; mi < 4; ++mi)
            #pragma unroll
            for (int r = 0; r < 4; ++r)
                Alds[(wm + mi * 16 + rr + r) * 64 + cl] = acc[mi][r];
    }
    __syncthreads();

    const int rbase = tid >> 4;            // 0..31
    const int cloc  = (tid & 15) * 4;      // col within tile
    const int cglob = bn0 + cloc;
    float4 bw = *(const float4*)(biasw + cglob);
    float4 av0 = *(const float4*)(alpha + 0 * H_SZ + cglob);
    float4 av1 = *(const float4*)(alpha + 1 * H_SZ + cglob);
    float4 av2 = *(const float4*)(alpha + 2 * H_SZ + cglob);
    float4 av3 = *(const float4*)(alpha + 3 * H_SZ + cglob);

    #pragma unroll 2
    for (int u = 0; u < 4; ++u) {
        int row = rbase + 32 * u;
        f32x4 a4 = *(const f32x4*)(Alds + row * 64 + cloc);
        const float* bsp = bs + (size_t)(bm0 + row) * (K_BR * H_SZ) + cglob;
        float4 b0 = *(const float4*)(bsp);
        float4 b1 = *(const float4*)(bsp + H_SZ);
        float4 b2 = *(const float4*)(bsp + 2 * H_SZ);
        float4 b3 = *(const float4*)(bsp + 3 * H_SZ);
        float v0 = a4[0] + bw.x + av0.x * b0.x + av1.x * b1.x + av2.x * b2.x + av3.x * b3.x;
        float v1 = a4[1] + bw.y + av0.y * b0.y + av1.y * b1.y + av2.y * b2.y + av3.y * b3.y;
        float v2 = a4[2] + bw.z + av0.z * b0.z + av1.z * b1.z + av2.z * b2.z + av3.z * b3.z;
        float v3 = a4[3] + bw.w + av0.w * b0.w + av1.w * b1.w + av2.w * b2.w + av3.w * b3.w;
        float s0 = 0.5f * v0 - 1.0f, s1 = 0.5f * v1 - 1.0f;
        float s2 = 0.5f * v2 - 1.0f, s3 = 0.5f * v3 - 1.0f;
        float4 o;
        o.x = (s0 >= 0.f) ? 1.f : 0.f;
        o.y = (s1 >= 0.f) ? 1.f : 0.f;
        o.z = (s2 >= 0.f) ? 1.f : 0.f;
        o.w = (s3 >= 0.f) ? 1.f : 0.f;
        *(float4*)(out + (size_t)(bm0 + row) * H_SZ + cglob) = o;
        int base = (bm0 + row) * H_SZ + cglob;
        if (fabsf(s0) < FIX_THR) { int sl = atomicAdd(cnt, 1); if (sl < MAXFIX) list[sl] = base;     }
        if (fabsf(s1) < FIX_THR) { int sl = atomicAdd(cnt, 1); if (sl < MAXFIX) list[sl] = base + 1; }
        if (fabsf(s2) < FIX_THR) { int sl = atomicAdd(cnt, 1); if (sl < MAXFIX) list[sl] = base + 2; }
        if (fabsf(s3) < FIX_THR) { int sl = atomicAdd(cnt, 1); if (sl < MAXFIX) list[sl] = base + 3; }
    }
}

// ---- fixup: exact fp32 recompute of flagged (row,col), one wave each ----
__global__ void fixup(const float* __restrict__ inp, const float* __restrict__ hid,
                      const float* __restrict__ bs, const float* __restrict__ W,
                      const float* __restrict__ bvec, const float* __restrict__ alpha,
                      const int* __restrict__ cnt, const int* __restrict__ list,
                      float* __restrict__ out) {
    int wave  = (blockIdx.x * blockDim.x + threadIdx.x) >> 6;
    int lane  = threadIdx.x & 63;
    int nwave = gridDim.x * (blockDim.x >> 6);
    int n = *cnt;
    if (n > MAXFIX) n = MAXFIX;
    for (int it = wave; it < n; it += nwave) {
        int idx = list[it];
        int row = idx >> 10, col = idx & 1023;
        float a[K_BR];
        #pragma unroll
        for (int k = 0; k < K_BR; ++k) a[k] = alpha[k * H_SZ + col];
        const float* xi = inp + (size_t)row * IN_SZ;
        const float* xh = hid + (size_t)row * H_SZ;
        float4 xv[8], wv[8];
        #pragma unroll
        for (int p = 0; p < 8; ++p) {
            int j = p * 256 + lane * 4;
            xv[p] = (p < 4) ? *(const float4*)(xi + j)
                            : *(const float4*)(xh + j - IN_SZ);
            int i = (p & 1) * 256 + lane * 4;
            wv[p] = *(const float4*)(W + ((size_t)((p >> 1) * H_SZ + col)) * BR_SZ + i);
        }
        float acc = 0.f;
        #pragma unroll
        for (int p = 0; p < 8; ++p) {
            float s = 1.f - a[p >> 1];
            acc += s * (xv[p].x * wv[p].x + xv[p].y * wv[p].y
                      + xv[p].z * wv[p].z + xv[p].w * wv[p].w);
        }
        #pragma unroll
        for (int off = 32; off; off >>= 1) acc += __shfl_xor(acc, off, 64);
        if (lane == 0) {
            float tot = acc;
            #pragma unroll
            for (int k = 0; k < K_BR; ++k)
                tot += (1.f - a[k]) * bvec[k * H_SZ + col]
                     + a[k] * bs[(size_t)row * (K_BR * H_SZ) + k * H_SZ + col];
            out[(size_t)row * H_SZ + col] = (0.5f * tot - 1.f >= 0.f) ? 1.f : 0.f;
        }
    }
}

// ---- fallback if workspace too small: direct fp32 (slow but correct) ----
__global__ void naive_kernel(const float* __restrict__ inp, const float* __restrict__ hid,
                             const float* __restrict__ bs, const float* __restrict__ W,
                             const float* __restrict__ bvec, const float* __restrict__ taus,
                             float* __restrict__ out) {
    int idx = blockIdx.x * 256 + threadIdx.x;
    if (idx >= B_SZ * H_SZ) return;
    int b = idx >> 10, h = idx & 1023;
    float tot = 0.f;
    for (int k = 0; k < K_BR; ++k) {
        const float* x = (k < 2) ? (inp + (size_t)b * IN_SZ + k * BR_SZ)
                                 : (hid + (size_t)b * H_SZ + (k - 2) * BR_SZ);
        const float* w = W + ((size_t)k * H_SZ + h) * BR_SZ;
        float d = 0.f;
        for (int i = 0; i < BR_SZ; ++i) d += x[i] * w[i];
        d += bvec[k * H_SZ + h];
        float a = 1.f / (1.f + expf(-taus[k * H_SZ + h]));
        tot += a * bs[(size_t)b * (K_BR * H_SZ) + k * H_SZ + h] + (1.f - a) * d;
    }
    out[idx] = (0.5f * tot - 1.f >= 0.f) ? 1.f : 0.f;
}

extern "C" void kernel_launch(void* const* d_in, const int* in_sizes, int n_in,
                              void* d_out, int out_size, void* d_ws, size_t ws_size,
                              hipStream_t stream) {
    const float* input_t = (const float*)d_in[0];
    const float* hidden  = (const float*)d_in[1];
    const float* bs      = (const float*)d_in[2];
    const float* W       = (const float*)d_in[3];
    const float* bvec    = (const float*)d_in[4];
    const float* taus    = (const float*)d_in[5];
    float* out = (float*)d_out;

    const size_t ALPHA_OFF = 0;
    const size_t BIAS_OFF  = 16 * 1024;
    const size_t CNT_OFF   = 32 * 1024;
    const size_t LIST_OFF  = 48 * 1024;
    const size_t WT_OFF    = LIST_OFF + (size_t)MAXFIX * 4;      // +4MB
    const size_t XB_OFF    = WT_OFF + (size_t)H_SZ * J_SZ * 2;   // +4MB
    const size_t WS_NEED   = XB_OFF + (size_t)B_SZ * J_SZ * 2;   // +32MB

    if (ws_size < WS_NEED) {
        naive_kernel<<<(B_SZ * H_SZ + 255) / 256, 256, 0, stream>>>(
            input_t, hidden, bs, W, bvec, taus, out);
        return;
    }

    float*          alphaw = (float*)((char*)d_ws + ALPHA_OFF);
    float*          biasw  = (float*)((char*)d_ws + BIAS_OFF);
    int*            cnt    = (int*)((char*)d_ws + CNT_OFF);
    int*            list   = (int*)((char*)d_ws + LIST_OFF);
    unsigned short* Wt     = (unsigned short*)((char*)d_ws + WT_OFF);
    unsigned short* Xb     = (unsigned short*)((char*)d_ws + XB_OFF);

    prep_alpha<<<4, 256, 0, stream>>>(taus, bvec, alphaw, biasw, cnt);
    build_wt<<<(H_SZ * J_SZ / 8 + 255) / 256, 256, 0, stream>>>(W, taus, Wt);
    build_xb<<<(B_SZ * J_SZ / 8 + 255) / 256, 256, 0, stream>>>(input_t, hidden, Xb);
    gemm_fused_ep<<<(B_SZ / BM) * (H_SZ / BN), 512, 0, stream>>>(
        Xb, Wt, alphaw, biasw, bs, out, cnt, list);
    fixup<<<2048, 256, 0, stream>>>(input_t, hidden, bs, W, bvec, alphaw, cnt, list, out);
}

// Round 9
// 91.917 us; speedup vs baseline: 1.3181x; 1.3181x over previous
//
#include <hip/hip_runtime.h>
#include <hip/hip_bf16.h>
#include <stdint.h>

#define B_SZ  8192
#define IN_SZ 1024
#define H_SZ  1024
#define K_BR  4
#define BR_SZ 512
#define J_SZ  2048   // IN + H (GEMM K dim)
#define BK    64     // K-step
#define NT    (J_SZ / BK)   // 32 K-tiles

#define FIX_THR 0.08f        // flag |0.5*v-1| < THR for exact fp32 recompute
#define MAXFIX  (1 << 20)    // 1M entries, 4MB

typedef __attribute__((ext_vector_type(8))) short  short8;   // 8 bf16
typedef __attribute__((ext_vector_type(4))) float  f32x4;

__device__ __forceinline__ unsigned short f2bf(float f) {
    union { __hip_bfloat16 b; unsigned short u; } cv;
    cv.b = __float2bfloat16(f);
    return cv.u;
}

__device__ __forceinline__ void gl_lds16(const void* g, void* l) {
    __builtin_amdgcn_global_load_lds(
        (const __attribute__((address_space(1))) void*)g,
        (__attribute__((address_space(3))) void*)l, 16, 0, 0);
}

// ---- prep: alpha = sigmoid(taus), biasw[h] = sum_k (1-alpha)*b[k,h]; zero cnt ----
__global__ void prep_alpha(const float* __restrict__ taus, const float* __restrict__ bvec,
                           float* __restrict__ alpha, float* __restrict__ biasw,
                           int* __restrict__ cnt) {
    int h = blockIdx.x * blockDim.x + threadIdx.x;
    if (h == 0) *cnt = 0;
    if (h >= H_SZ) return;
    float bsum = 0.f;
    for (int k = 0; k < K_BR; ++k) {
        float a = 1.f / (1.f + expf(-taus[k * H_SZ + h]));
        alpha[k * H_SZ + h] = a;
        bsum += (1.f - a) * bvec[k * H_SZ + h];
    }
    biasw[h] = bsum;
}

// ---- prep 2: Wt[h][k*512+i] = (1-sigmoid(taus[k,h])) * W[k,h,i]  (bf16, B^T) ----
__global__ void build_wt(const float* __restrict__ W, const float* __restrict__ taus,
                         unsigned short* __restrict__ Wt) {
    int t = blockIdx.x * 256 + threadIdx.x;
    int e0 = t * 8;
    if (e0 >= H_SZ * J_SZ) return;
    int h  = e0 >> 11;
    int j0 = e0 & 2047;
    int k  = j0 >> 9;
    int i0 = j0 & 511;
    float a = 1.f / (1.f + expf(-taus[k * H_SZ + h]));
    float s = 1.f - a;
    const float* src = W + ((size_t)(k * H_SZ + h)) * BR_SZ + i0;
    union { short8 v; unsigned short u[8]; } o;
    #pragma unroll
    for (int q = 0; q < 8; ++q) o.u[q] = f2bf(s * src[q]);
    *(short8*)(Wt + (size_t)h * J_SZ + j0) = o.v;
}

// ---- main: 128x128 bf16 MFMA GEMM (r7 structure); A staged fp32->bf16 in-register
//      (kills build_xb); B via gl_lds from pre-swizzled Wt; fused epilogue ----
__global__ void __launch_bounds__(512, 4)
gemm_fused_ep(const float* __restrict__ inp,
              const float* __restrict__ hid,
              const unsigned short* __restrict__ Wt,
              const float* __restrict__ alpha,
              const float* __restrict__ biasw,
              const float* __restrict__ bs,
              float* __restrict__ out,
              int* __restrict__ cnt,
              int* __restrict__ list) {
    __shared__ char smem[65536];   // A dbuf 32KB | B dbuf 32KB ; epilogue overlay f32[128][128]
    const int tid  = threadIdx.x;
    const int wid  = tid >> 6;          // 0..7
    const int lane = tid & 63;
    const int bm0  = blockIdx.x * 128;
    const int bn0  = blockIdx.y * 128;
    const int wm   = (wid >> 2) * 64;   // 2 wave-rows of 64
    const int wn   = (wid & 3) * 32;    // 4 wave-cols of 32

    f32x4 acc[4][2];
    #pragma unroll
    for (int mi = 0; mi < 4; ++mi)
        #pragma unroll
        for (int ni = 0; ni < 2; ++ni)
            acc[mi][ni] = (f32x4){0.f, 0.f, 0.f, 0.f};

    const int hi = lane >> 4;     // 0..3 k-slot selector
    const int rm = lane & 15;

    // B staging (gl_lds): chunk c covers rows c*8..c*8+7; lane l -> base + l*16
    const int srow  = lane >> 3;
    const int sslot = lane & 7;
    // A reg staging: thread -> row ar (0..127), slots as0, as0+1 (linear global src)
    const int ar  = tid >> 2;
    const int as0 = (tid & 3) * 2;
    const int aw0 = (as0     ^ (ar & 7)) << 4;   // swizzled LDS byte slot
    const int aw1 = ((as0+1) ^ (ar & 7)) << 4;

#define AB(b) ((char*)smem + (b) * 16384)
#define BB(b) ((char*)smem + 32768 + (b) * 16384)

#define A_LOAD(kt)                                                            \
    {                                                                         \
        const float* sA = ((kt) < IN_SZ)                                      \
            ? (inp + (size_t)(bm0 + ar) * IN_SZ + (kt))                       \
            : (hid + (size_t)(bm0 + ar) * H_SZ + ((kt) - IN_SZ));             \
        a0_ = *(const float4*)(sA + as0 * 8);                                 \
        a1_ = *(const float4*)(sA + as0 * 8 + 4);                             \
        a2_ = *(const float4*)(sA + as0 * 8 + 8);                             \
        a3_ = *(const float4*)(sA + as0 * 8 + 12);                            \
    }

#define A_WRITE(b)                                                            \
    {                                                                         \
        union { short8 v; unsigned short u[8]; } w0, w1;                      \
        w0.u[0] = f2bf(a0_.x); w0.u[1] = f2bf(a0_.y);                         \
        w0.u[2] = f2bf(a0_.z); w0.u[3] = f2bf(a0_.w);                         \
        w0.u[4] = f2bf(a1_.x); w0.u[5] = f2bf(a1_.y);                         \
        w0.u[6] = f2bf(a1_.z); w0.u[7] = f2bf(a1_.w);                         \
        w1.u[0] = f2bf(a2_.x); w1.u[1] = f2bf(a2_.y);                         \
        w1.u[2] = f2bf(a2_.z); w1.u[3] = f2bf(a2_.w);                         \
        w1.u[4] = f2bf(a3_.x); w1.u[5] = f2bf(a3_.y);                         \
        w1.u[6] = f2bf(a3_.z); w1.u[7] = f2bf(a3_.w);                         \
        *(short8*)(AB(b) + ar * 128 + aw0) = w0.v;                            \
        *(short8*)(AB(b) + ar * 128 + aw1) = w1.v;                            \
    }

#define B_STAGE(kt, b)                                                        \
    {                                                                         \
        _Pragma("unroll")                                                     \
        for (int p = 0; p < 2; ++p) {                                         \
            int c    = wid * 2 + p;                                           \
            int row  = c * 8 + srow;                                          \
            int sw   = sslot ^ (row & 7);                                     \
            gl_lds16(Wt + (size_t)(bn0 + row) * J_SZ + (kt) + sw * 8,         \
                     BB(b) + c * 1024);                                       \
        }                                                                     \
    }

    float4 a0_, a1_, a2_, a3_;

    // prologue: stage tile 0
    A_LOAD(0);
    A_WRITE(0);
    B_STAGE(0, 0);
    __syncthreads();

    int cur = 0;
    for (int t = 0; t < NT; ++t) {
        const int ktn = (t + 1) * BK;
        if (t + 1 < NT) {
            A_LOAD(ktn);             // issue fp32 loads; latency hidden under MFMAs
            B_STAGE(ktn, cur ^ 1);   // async B into other buffer
        }

        #pragma unroll
        for (int h2 = 0; h2 < 2; ++h2) {        // k halves 0..31, 32..63
            const int s0 = h2 * 4 + hi;         // 16B slot pre-swizzle
            short8 af[4], bf[2];
            #pragma unroll
            for (int mi = 0; mi < 4; ++mi) {
                int m = wm + mi * 16 + rm;
                af[mi] = *(const short8*)(AB(cur) + m * 128 + ((s0 ^ (m & 7)) << 4));
            }
            #pragma unroll
            for (int ni = 0; ni < 2; ++ni) {
                int n = wn + ni * 16 + rm;
                bf[ni] = *(const short8*)(BB(cur) + n * 128 + ((s0 ^ (n & 7)) << 4));
            }
            #pragma unroll
            for (int mi = 0; mi < 4; ++mi)
                #pragma unroll
                for (int ni = 0; ni < 2; ++ni)
                    acc[mi][ni] = __builtin_amdgcn_mfma_f32_16x16x32_bf16(
                                      af[mi], bf[ni], acc[mi][ni], 0, 0, 0);
        }

        if (t + 1 < NT) A_WRITE(cur ^ 1);   // cvt + swizzled ds_write for next tile
        __syncthreads();                    // drains ds_writes + gl_lds, barrier
        cur ^= 1;
    }
#undef A_LOAD
#undef A_WRITE
#undef B_STAGE
#undef AB
#undef BB

    // ---- fused epilogue: acc -> LDS overlay, coalesced bias+bs+spike+flag ----
    float* Alds = (float*)smem;            // f32[128][128], 64KB (A/B bufs dead)
    const int rr = hi * 4;                 // C/D row base: (lane>>4)*4 + reg
    #pragma unroll
    for (int ni = 0; ni < 2; ++ni) {
        int cl = wn + ni * 16 + rm;
        #pragma unroll
        for (int mi = 0; mi < 4; ++mi)
            #pragma unroll
            for (int r = 0; r < 4; ++r)
                Alds[(wm + mi * 16 + rr + r) * 128 + cl] = acc[mi][ni][r];
    }
    __syncthreads();

    const int rbase = tid >> 5;            // 0..15
    const int cloc  = (tid & 31) * 4;      // col within tile
    const int cglob = bn0 + cloc;
    float4 bw = *(const float4*)(biasw + cglob);
    float4 av0 = *(const float4*)(alpha + 0 * H_SZ + cglob);
    float4 av1 = *(const float4*)(alpha + 1 * H_SZ + cglob);
    float4 av2 = *(const float4*)(alpha + 2 * H_SZ + cglob);
    float4 av3 = *(const float4*)(alpha + 3 * H_SZ + cglob);

    #pragma unroll 2
    for (int u = 0; u < 8; ++u) {
        int row = rbase + 16 * u;
        f32x4 a4 = *(const f32x4*)(Alds + row * 128 + cloc);
        const float* bsp = bs + (size_t)(bm0 + row) * (K_BR * H_SZ) + cglob;
        float4 b0 = *(const float4*)(bsp);
        float4 b1 = *(const float4*)(bsp + H_SZ);
        float4 b2 = *(const float4*)(bsp + 2 * H_SZ);
        float4 b3 = *(const float4*)(bsp + 3 * H_SZ);
        float v0 = a4[0] + bw.x + av0.x * b0.x + av1.x * b1.x + av2.x * b2.x + av3.x * b3.x;
        float v1 = a4[1] + bw.y + av0.y * b0.y + av1.y * b1.y + av2.y * b2.y + av3.y * b3.y;
        float v2 = a4[2] + bw.z + av0.z * b0.z + av1.z * b1.z + av2.z * b2.z + av3.z * b3.z;
        float v3 = a4[3] + bw.w + av0.w * b0.w + av1.w * b1.w + av2.w * b2.w + av3.w * b3.w;
        float s0 = 0.5f * v0 - 1.0f, s1 = 0.5f * v1 - 1.0f;
        float s2 = 0.5f * v2 - 1.0f, s3 = 0.5f * v3 - 1.0f;
        float4 o;
        o.x = (s0 >= 0.f) ? 1.f : 0.f;
        o.y = (s1 >= 0.f) ? 1.f : 0.f;
        o.z = (s2 >= 0.f) ? 1.f : 0.f;
        o.w = (s3 >= 0.f) ? 1.f : 0.f;
        *(float4*)(out + (size_t)(bm0 + row) * H_SZ + cglob) = o;
        int base = (bm0 + row) * H_SZ + cglob;
        if (fabsf(s0) < FIX_THR) { int sl = atomicAdd(cnt, 1); if (sl < MAXFIX) list[sl] = base;     }
        if (fabsf(s1) < FIX_THR) { int sl = atomicAdd(cnt, 1); if (sl < MAXFIX) list[sl] = base + 1; }
        if (fabsf(s2) < FIX_THR) { int sl = atomicAdd(cnt, 1); if (sl < MAXFIX) list[sl] = base + 2; }
        if (fabsf(s3) < FIX_THR) { int sl = atomicAdd(cnt, 1); if (sl < MAXFIX) list[sl] = base + 3; }
    }
}

// ---- fixup: exact fp32 recompute of flagged (row,col), one wave each ----
__global__ void fixup(const float* __restrict__ inp, const float* __restrict__ hid,
                      const float* __restrict__ bs, const float* __restrict__ W,
                      const float* __restrict__ bvec, const float* __restrict__ alpha,
                      const int* __restrict__ cnt, const int* __restrict__ list,
                      float* __restrict__ out) {
    int wave  = (blockIdx.x * blockDim.x + threadIdx.x) >> 6;
    int lane  = threadIdx.x & 63;
    int nwave = gridDim.x * (blockDim.x >> 6);
    int n = *cnt;
    if (n > MAXFIX) n = MAXFIX;
    for (int it = wave; it < n; it += nwave) {
        int idx = list[it];
        int row = idx >> 10, col = idx & 1023;
        float a[K_BR];
        #pragma unroll
        for (int k = 0; k < K_BR; ++k) a[k] = alpha[k * H_SZ + col];
        const float* xi = inp + (size_t)row * IN_SZ;
        const float* xh = hid + (size_t)row * H_SZ;
        float4 xv[8], wv[8];
        #pragma unroll
        for (int p = 0; p < 8; ++p) {
            int j = p * 256 + lane * 4;
            xv[p] = (p < 4) ? *(const float4*)(xi + j)
                            : *(const float4*)(xh + j - IN_SZ);
            int i = (p & 1) * 256 + lane * 4;
            wv[p] = *(const float4*)(W + ((size_t)((p >> 1) * H_SZ + col)) * BR_SZ + i);
        }
        float acc = 0.f;
        #pragma unroll
        for (int p = 0; p < 8; ++p) {
            float s = 1.f - a[p >> 1];
            acc += s * (xv[p].x * wv[p].x + xv[p].y * wv[p].y
                      + xv[p].z * wv[p].z + xv[p].w * wv[p].w);
        }
        #pragma unroll
        for (int off = 32; off; off >>= 1) acc += __shfl_xor(acc, off, 64);
        if (lane == 0) {
            float tot = acc;
            #pragma unroll
            for (int k = 0; k < K_BR; ++k)
                tot += (1.f - a[k]) * bvec[k * H_SZ + col]
                     + a[k] * bs[(size_t)row * (K_BR * H_SZ) + k * H_SZ + col];
            out[(size_t)row * H_SZ + col] = (0.5f * tot - 1.f >= 0.f) ? 1.f : 0.f;
        }
    }
}

// ---- fallback if workspace too small: direct fp32 (slow but correct) ----
__global__ void naive_kernel(const float* __restrict__ inp, const float* __restrict__ hid,
                             const float* __restrict__ bs, const float* __restrict__ W,
                             const float* __restrict__ bvec, const float* __restrict__ taus,
                             float* __restrict__ out) {
    int idx = blockIdx.x * 256 + threadIdx.x;
    if (idx >= B_SZ * H_SZ) return;
    int b = idx >> 10, h = idx & 1023;
    float tot = 0.f;
    for (int k = 0; k < K_BR; ++k) {
        const float* x = (k < 2) ? (inp + (size_t)b * IN_SZ + k * BR_SZ)
                                 : (hid + (size_t)b * H_SZ + (k - 2) * BR_SZ);
        const float* w = W + ((size_t)k * H_SZ + h) * BR_SZ;
        float d = 0.f;
        for (int i = 0; i < BR_SZ; ++i) d += x[i] * w[i];
        d += bvec[k * H_SZ + h];
        float a = 1.f / (1.f + expf(-taus[k * H_SZ + h]));
        tot += a * bs[(size_t)b * (K_BR * H_SZ) + k * H_SZ + h] + (1.f - a) * d;
    }
    out[idx] = (0.5f * tot - 1.f >= 0.f) ? 1.f : 0.f;
}

extern "C" void kernel_launch(void* const* d_in, const int* in_sizes, int n_in,
                              void* d_out, int out_size, void* d_ws, size_t ws_size,
                              hipStream_t stream) {
    const float* input_t = (const float*)d_in[0];
    const float* hidden  = (const float*)d_in[1];
    const float* bs      = (const float*)d_in[2];
    const float* W       = (const float*)d_in[3];
    const float* bvec    = (const float*)d_in[4];
    const float* taus    = (const float*)d_in[5];
    float* out = (float*)d_out;

    const size_t ALPHA_OFF = 0;
    const size_t BIAS_OFF  = 16 * 1024;
    const size_t CNT_OFF   = 32 * 1024;
    const size_t LIST_OFF  = 48 * 1024;
    const size_t WT_OFF    = LIST_OFF + (size_t)MAXFIX * 4;      // +4MB
    const size_t WS_NEED   = WT_OFF + (size_t)H_SZ * J_SZ * 2;   // +4MB

    if (ws_size < WS_NEED) {
        naive_kernel<<<(B_SZ * H_SZ + 255) / 256, 256, 0, stream>>>(
            input_t, hidden, bs, W, bvec, taus, out);
        return;
    }

    float*          alphaw = (float*)((char*)d_ws + ALPHA_OFF);
    float*          biasw  = (float*)((char*)d_ws + BIAS_OFF);
    int*            cnt    = (int*)((char*)d_ws + CNT_OFF);
    int*            list   = (int*)((char*)d_ws + LIST_OFF);
    unsigned short* Wt     = (unsigned short*)((char*)d_ws + WT_OFF);

    prep_alpha<<<4, 256, 0, stream>>>(taus, bvec, alphaw, biasw, cnt);
    build_wt<<<(H_SZ * J_SZ / 8 + 255) / 256, 256, 0, stream>>>(W, taus, Wt);
    gemm_fused_ep<<<dim3(B_SZ / 128, H_SZ / 128), 512, 0, stream>>>(
        input_t, hidden, Wt, alphaw, biasw, bs, out, cnt, list);
    fixup<<<2048, 256, 0, stream>>>(input_t, hidden, bs, W, bvec, alphaw, cnt, list, out);
}

// Round 10
// 89.487 us; speedup vs baseline: 1.3539x; 1.0272x over previous
//
#include <hip/hip_runtime.h>
#include <hip/hip_bf16.h>
#include <stdint.h>

#define B_SZ  8192
#define IN_SZ 1024
#define H_SZ  1024
#define K_BR  4
#define BR_SZ 512
#define J_SZ  2048   // IN + H (GEMM K dim)
#define BK    64     // K-step
#define NT    (J_SZ / BK)   // 32 K-tiles

#define FIX_THR 0.08f        // flag |0.5*v-1| < THR for exact fp32 recompute
#define MAXFIX  (1 << 20)    // 1M entries, 4MB

typedef __attribute__((ext_vector_type(8))) short  short8;   // 8 bf16
typedef __attribute__((ext_vector_type(4))) float  f32x4;

__device__ __forceinline__ unsigned short f2bf(float f) {
    union { __hip_bfloat16 b; unsigned short u; } cv;
    cv.b = __float2bfloat16(f);
    return cv.u;
}

__device__ __forceinline__ void gl_lds16(const void* g, void* l) {
    __builtin_amdgcn_global_load_lds(
        (const __attribute__((address_space(1))) void*)g,
        (__attribute__((address_space(3))) void*)l, 16, 0, 0);
}

// ---- prep: alpha = sigmoid(taus), biasw[h] = sum_k (1-alpha)*b[k,h]; zero cnt ----
__global__ void prep_alpha(const float* __restrict__ taus, const float* __restrict__ bvec,
                           float* __restrict__ alpha, float* __restrict__ biasw,
                           int* __restrict__ cnt) {
    int h = blockIdx.x * blockDim.x + threadIdx.x;
    if (h == 0) *cnt = 0;
    if (h >= H_SZ) return;
    float bsum = 0.f;
    for (int k = 0; k < K_BR; ++k) {
        float a = 1.f / (1.f + expf(-taus[k * H_SZ + h]));
        alpha[k * H_SZ + h] = a;
        bsum += (1.f - a) * bvec[k * H_SZ + h];
    }
    biasw[h] = bsum;
}

// ---- prep 2: Wt[h][k*512+i] = (1-sigmoid(taus[k,h])) * W[k,h,i]  (bf16, B^T) ----
__global__ void build_wt(const float* __restrict__ W, const float* __restrict__ taus,
                         unsigned short* __restrict__ Wt) {
    int t = blockIdx.x * 256 + threadIdx.x;
    int e0 = t * 8;
    if (e0 >= H_SZ * J_SZ) return;
    int h  = e0 >> 11;
    int j0 = e0 & 2047;
    int k  = j0 >> 9;
    int i0 = j0 & 511;
    float a = 1.f / (1.f + expf(-taus[k * H_SZ + h]));
    float s = 1.f - a;
    const float* src = W + ((size_t)(k * H_SZ + h)) * BR_SZ + i0;
    union { short8 v; unsigned short u[8]; } o;
    #pragma unroll
    for (int q = 0; q < 8; ++q) o.u[q] = f2bf(s * src[q]);
    *(short8*)(Wt + (size_t)h * J_SZ + j0) = o.v;
}

// ---- prep 3: Xb[b][j] = bf16(concat(input_t, hidden)[b][j]) ----
__global__ void build_xb(const float* __restrict__ inp, const float* __restrict__ hid,
                         unsigned short* __restrict__ Xb) {
    int t = blockIdx.x * 256 + threadIdx.x;
    long long e0 = (long long)t * 8;
    if (e0 >= (long long)B_SZ * J_SZ) return;
    int b  = (int)(e0 >> 11);
    int j0 = (int)(e0 & 2047);
    const float* src = (j0 < IN_SZ) ? (inp + (size_t)b * IN_SZ + j0)
                                    : (hid + (size_t)b * H_SZ + (j0 - IN_SZ));
    union { short8 v; unsigned short u[8]; } o;
    #pragma unroll
    for (int q = 0; q < 8; ++q) o.u[q] = f2bf(src[q]);
    *(short8*)(Xb + (size_t)b * J_SZ + j0) = o.v;
}

// ---- main: 128x128 bf16 MFMA GEMM (r7 structure) with COUNTED-VMCNT two-barrier
//      pipeline (T4): next-tile gl_lds stay in flight across the barrier. ----
__global__ void __launch_bounds__(512, 4)
gemm_fused_ep(const unsigned short* __restrict__ Xb,
              const unsigned short* __restrict__ Wt,
              const float* __restrict__ alpha,
              const float* __restrict__ biasw,
              const float* __restrict__ bs,
              float* __restrict__ out,
              int* __restrict__ cnt,
              int* __restrict__ list) {
    __shared__ char smem[65536];   // A dbuf 32KB | B dbuf 32KB ; epilogue overlay f32[128][128]
    const int tid  = threadIdx.x;
    const int wid  = tid >> 6;          // 0..7
    const int lane = tid & 63;
    const int bm0  = blockIdx.x * 128;
    const int bn0  = blockIdx.y * 128;
    const int wm   = (wid >> 2) * 64;   // 2 wave-rows of 64
    const int wn   = (wid & 3) * 32;    // 4 wave-cols of 32

    f32x4 acc[4][2];
    #pragma unroll
    for (int mi = 0; mi < 4; ++mi)
        #pragma unroll
        for (int ni = 0; ni < 2; ++ni)
            acc[mi][ni] = (f32x4){0.f, 0.f, 0.f, 0.f};

    const int hi = lane >> 4;     // 0..3 k-slot selector
    const int rm = lane & 15;

    const int srow  = lane >> 3;  // row within chunk
    const int sslot = lane & 7;   // 16B slot within 128B row

#define AB(b) ((char*)smem + (b) * 16384)
#define BB(b) ((char*)smem + 32768 + (b) * 16384)

// 4 gl_lds per wave per STAGE (2 A chunks + 2 B chunks) -> vmcnt N = 4
#define STAGE(kt, b)                                                          \
    {                                                                         \
        _Pragma("unroll")                                                     \
        for (int p = 0; p < 2; ++p) {                                         \
            int c    = wid * 2 + p;                                           \
            int row  = c * 8 + srow;                                          \
            int sw   = sslot ^ (row & 7);                                     \
            gl_lds16(Xb + (size_t)(bm0 + row) * J_SZ + (kt) + sw * 8,         \
                     AB(b) + c * 1024);                                       \
            gl_lds16(Wt + (size_t)(bn0 + row) * J_SZ + (kt) + sw * 8,         \
                     BB(b) + c * 1024);                                       \
        }                                                                     \
    }

    STAGE(0, 0);

    int cur = 0;
    for (int t = 0; t < NT; ++t) {
        if (t + 1 < NT) {
            STAGE((t + 1) * BK, cur ^ 1);   // 4 more in flight (8 total)
            asm volatile("s_waitcnt vmcnt(4)" ::: "memory");  // tile t landed; t+1 stays in flight
        } else {
            asm volatile("s_waitcnt vmcnt(0)" ::: "memory");  // final drain
        }
        __builtin_amdgcn_s_barrier();       // buf cur complete for all waves
        __builtin_amdgcn_sched_barrier(0);

        #pragma unroll
        for (int h2 = 0; h2 < 2; ++h2) {        // k halves 0..31, 32..63
            const int s0 = h2 * 4 + hi;         // 16B slot pre-swizzle
            short8 af[4], bf[2];
            #pragma unroll
            for (int mi = 0; mi < 4; ++mi) {
                int m = wm + mi * 16 + rm;
                af[mi] = *(const short8*)(AB(cur) + m * 128 + ((s0 ^ (m & 7)) << 4));
            }
            #pragma unroll
            for (int ni = 0; ni < 2; ++ni) {
                int n = wn + ni * 16 + rm;
                bf[ni] = *(const short8*)(BB(cur) + n * 128 + ((s0 ^ (n & 7)) << 4));
            }
            #pragma unroll
            for (int mi = 0; mi < 4; ++mi)
                #pragma unroll
                for (int ni = 0; ni < 2; ++ni)
                    acc[mi][ni] = __builtin_amdgcn_mfma_f32_16x16x32_bf16(
                                      af[mi], bf[ni], acc[mi][ni], 0, 0, 0);
        }

        asm volatile("s_waitcnt lgkmcnt(0)" ::: "memory");  // my ds_reads retired
        __builtin_amdgcn_s_barrier();       // safe for next iter to overwrite cur
        cur ^= 1;
    }
#undef STAGE
#undef AB
#undef BB

    // ---- fused epilogue: acc -> LDS overlay, coalesced bias+bs+spike+flag ----
    float* Alds = (float*)smem;            // f32[128][128], 64KB (A/B bufs dead; vmcnt drained)
    const int rr = hi * 4;                 // C/D row base: (lane>>4)*4 + reg
    #pragma unroll
    for (int ni = 0; ni < 2; ++ni) {
        int cl = wn + ni * 16 + rm;
        #pragma unroll
        for (int mi = 0; mi < 4; ++mi)
            #pragma unroll
            for (int r = 0; r < 4; ++r)
                Alds[(wm + mi * 16 + rr + r) * 128 + cl] = acc[mi][ni][r];
    }
    __syncthreads();

    const int rbase = tid >> 5;            // 0..15
    const int cloc  = (tid & 31) * 4;      // col within tile
    const int cglob = bn0 + cloc;
    float4 bw = *(const float4*)(biasw + cglob);
    float4 av0 = *(const float4*)(alpha + 0 * H_SZ + cglob);
    float4 av1 = *(const float4*)(alpha + 1 * H_SZ + cglob);
    float4 av2 = *(const float4*)(alpha + 2 * H_SZ + cglob);
    float4 av3 = *(const float4*)(alpha + 3 * H_SZ + cglob);

    #pragma unroll 2
    for (int u = 0; u < 8; ++u) {
        int row = rbase + 16 * u;
        f32x4 a4 = *(const f32x4*)(Alds + row * 128 + cloc);
        const float* bsp = bs + (size_t)(bm0 + row) * (K_BR * H_SZ) + cglob;
        float4 b0 = *(const float4*)(bsp);
        float4 b1 = *(const float4*)(bsp + H_SZ);
        float4 b2 = *(const float4*)(bsp + 2 * H_SZ);
        float4 b3 = *(const float4*)(bsp + 3 * H_SZ);
        float v0 = a4[0] + bw.x + av0.x * b0.x + av1.x * b1.x + av2.x * b2.x + av3.x * b3.x;
        float v1 = a4[1] + bw.y + av0.y * b0.y + av1.y * b1.y + av2.y * b2.y + av3.y * b3.y;
        float v2 = a4[2] + bw.z + av0.z * b0.z + av1.z * b1.z + av2.z * b2.z + av3.z * b3.z;
        float v3 = a4[3] + bw.w + av0.w * b0.w + av1.w * b1.w + av2.w * b2.w + av3.w * b3.w;
        float s0 = 0.5f * v0 - 1.0f, s1 = 0.5f * v1 - 1.0f;
        float s2 = 0.5f * v2 - 1.0f, s3 = 0.5f * v3 - 1.0f;
        float4 o;
        o.x = (s0 >= 0.f) ? 1.f : 0.f;
        o.y = (s1 >= 0.f) ? 1.f : 0.f;
        o.z = (s2 >= 0.f) ? 1.f : 0.f;
        o.w = (s3 >= 0.f) ? 1.f : 0.f;
        *(float4*)(out + (size_t)(bm0 + row) * H_SZ + cglob) = o;
        int base = (bm0 + row) * H_SZ + cglob;
        if (fabsf(s0) < FIX_THR) { int sl = atomicAdd(cnt, 1); if (sl < MAXFIX) list[sl] = base;     }
        if (fabsf(s1) < FIX_THR) { int sl = atomicAdd(cnt, 1); if (sl < MAXFIX) list[sl] = base + 1; }
        if (fabsf(s2) < FIX_THR) { int sl = atomicAdd(cnt, 1); if (sl < MAXFIX) list[sl] = base + 2; }
        if (fabsf(s3) < FIX_THR) { int sl = atomicAdd(cnt, 1); if (sl < MAXFIX) list[sl] = base + 3; }
    }
}

// ---- fixup: exact fp32 recompute of flagged (row,col), one wave each ----
__global__ void fixup(const float* __restrict__ inp, const float* __restrict__ hid,
                      const float* __restrict__ bs, const float* __restrict__ W,
                      const float* __restrict__ bvec, const float* __restrict__ alpha,
                      const int* __restrict__ cnt, const int* __restrict__ list,
                      float* __restrict__ out) {
    int wave  = (blockIdx.x * blockDim.x + threadIdx.x) >> 6;
    int lane  = threadIdx.x & 63;
    int nwave = gridDim.x * (blockDim.x >> 6);
    int n = *cnt;
    if (n > MAXFIX) n = MAXFIX;
    for (int it = wave; it < n; it += nwave) {
        int idx = list[it];
        int row = idx >> 10, col = idx & 1023;
        float a[K_BR];
        #pragma unroll
        for (int k = 0; k < K_BR; ++k) a[k] = alpha[k * H_SZ + col];
        const float* xi = inp + (size_t)row * IN_SZ;
        const float* xh = hid + (size_t)row * H_SZ;
        float4 xv[8], wv[8];
        #pragma unroll
        for (int p = 0; p < 8; ++p) {
            int j = p * 256 + lane * 4;
            xv[p] = (p < 4) ? *(const float4*)(xi + j)
                            : *(const float4*)(xh + j - IN_SZ);
            int i = (p & 1) * 256 + lane * 4;
            wv[p] = *(const float4*)(W + ((size_t)((p >> 1) * H_SZ + col)) * BR_SZ + i);
        }
        float acc = 0.f;
        #pragma unroll
        for (int p = 0; p < 8; ++p) {
            float s = 1.f - a[p >> 1];
            acc += s * (xv[p].x * wv[p].x + xv[p].y * wv[p].y
                      + xv[p].z * wv[p].z + xv[p].w * wv[p].w);
        }
        #pragma unroll
        for (int off = 32; off; off >>= 1) acc += __shfl_xor(acc, off, 64);
        if (lane == 0) {
            float tot = acc;
            #pragma unroll
            for (int k = 0; k < K_BR; ++k)
                tot += (1.f - a[k]) * bvec[k * H_SZ + col]
                     + a[k] * bs[(size_t)row * (K_BR * H_SZ) + k * H_SZ + col];
            out[(size_t)row * H_SZ + col] = (0.5f * tot - 1.f >= 0.f) ? 1.f : 0.f;
        }
    }
}

// ---- fallback if workspace too small: direct fp32 (slow but correct) ----
__global__ void naive_kernel(const float* __restrict__ inp, const float* __restrict__ hid,
                             const float* __restrict__ bs, const float* __restrict__ W,
                             const float* __restrict__ bvec, const float* __restrict__ taus,
                             float* __restrict__ out) {
    int idx = blockIdx.x * 256 + threadIdx.x;
    if (idx >= B_SZ * H_SZ) return;
    int b = idx >> 10, h = idx & 1023;
    float tot = 0.f;
    for (int k = 0; k < K_BR; ++k) {
        const float* x = (k < 2) ? (inp + (size_t)b * IN_SZ + k * BR_SZ)
                                 : (hid + (size_t)b * H_SZ + (k - 2) * BR_SZ);
        const float* w = W + ((size_t)k * H_SZ + h) * BR_SZ;
        float d = 0.f;
        for (int i = 0; i < BR_SZ; ++i) d += x[i] * w[i];
        d += bvec[k * H_SZ + h];
        float a = 1.f / (1.f + expf(-taus[k * H_SZ + h]));
        tot += a * bs[(size_t)b * (K_BR * H_SZ) + k * H_SZ + h] + (1.f - a) * d;
    }
    out[idx] = (0.5f * tot - 1.f >= 0.f) ? 1.f : 0.f;
}

extern "C" void kernel_launch(void* const* d_in, const int* in_sizes, int n_in,
                              void* d_out, int out_size, void* d_ws, size_t ws_size,
                              hipStream_t stream) {
    const float* input_t = (const float*)d_in[0];
    const float* hidden  = (const float*)d_in[1];
    const float* bs      = (const float*)d_in[2];
    const float* W       = (const float*)d_in[3];
    const float* bvec    = (const float*)d_in[4];
    const float* taus    = (const float*)d_in[5];
    float* out = (float*)d_out;

    const size_t ALPHA_OFF = 0;
    const size_t BIAS_OFF  = 16 * 1024;
    const size_t CNT_OFF   = 32 * 1024;
    const size_t LIST_OFF  = 48 * 1024;
    const size_t WT_OFF    = LIST_OFF + (size_t)MAXFIX * 4;      // +4MB
    const size_t XB_OFF    = WT_OFF + (size_t)H_SZ * J_SZ * 2;   // +4MB
    const size_t WS_NEED   = XB_OFF + (size_t)B_SZ * J_SZ * 2;   // +32MB

    if (ws_size < WS_NEED) {
        naive_kernel<<<(B_SZ * H_SZ + 255) / 256, 256, 0, stream>>>(
            input_t, hidden, bs, W, bvec, taus, out);
        return;
    }

    float*          alphaw = (float*)((char*)d_ws + ALPHA_OFF);
    float*          biasw  = (float*)((char*)d_ws + BIAS_OFF);
    int*            cnt    = (int*)((char*)d_ws + CNT_OFF);
    int*            list   = (int*)((char*)d_ws + LIST_OFF);
    unsigned short* Wt     = (unsigned short*)((char*)d_ws + WT_OFF);
    unsigned short* Xb     = (unsigned short*)((char*)d_ws + XB_OFF);

    prep_alpha<<<4, 256, 0, stream>>>(taus, bvec, alphaw, biasw, cnt);
    build_wt<<<(H_SZ * J_SZ / 8 + 255) / 256, 256, 0, stream>>>(W, taus, Wt);
    build_xb<<<(B_SZ * J_SZ / 8 + 255) / 256, 256, 0, stream>>>(input_t, hidden, Xb);
    gemm_fused_ep<<<dim3(B_SZ / 128, H_SZ / 128), 512, 0, stream>>>(
        Xb, Wt, alphaw, biasw, bs, out, cnt, list);
    fixup<<<2048, 256, 0, stream>>>(input_t, hidden, bs, W, bvec, alphaw, cnt, list, out);
}